// Round 6
// baseline (109.149 us; speedup 1.0000x reference)
//
#include <hip/hip_runtime.h>
#include <hip/hip_fp16.h>
#include <stdint.h>

// MultiResolutionHashEncoding, R6: all-levels-per-block restructure.
// Evidence R2-R5: level-split structure plateaus at ~30-37 us with every pipe
// <25% busy — cost is summed per-level waste (weights x16, x-reads x16, ws
// round-trip + transpose kernel for coalesced output). New shape: block owns
// 512 points for ALL 16 levels; per level, stage the f16 table (prep kernel)
// into one 64 KiB LDS buffer via global_load_lds (no ds-issue), gather, FMA
// into 32 accumulator regs; next level's hash precomputed inside the staging
// shadow. Output: 128 B contiguous per thread, no second pass.

#define NUM_LEVELS 16
#define TABLE_SZ   16384
#define BLOCK      512

// prep: f32 tables -> f16 half2 (1 MB) in workspace
__global__ __launch_bounds__(256)
void prep_kernel(const float* __restrict__ tables, __half2* __restrict__ wst)
{
    int e = blockIdx.x * 256 + threadIdx.x;      // 0 .. 16*16384-1
    float2 v = ((const float2*)tables)[e];
    wst[e] = __floats2half2_rn(v.x, v.y);
}

__device__ __forceinline__ void make_hash(float px, float py, float pz, float r,
                                          uint32_t& h0, uint32_t& h1, uint32_t& h2,
                                          uint32_t& h3, uint32_t& h4, uint32_t& h5)
{
    float sx = r * px, sy = r * py, sz = r * pz;
    // int32 wraparound hash == uint32 arithmetic; mask/shift distribute over
    // XOR -> pre-shifted byte offsets (half2 = 4 B -> <<2). ceil, NOT lo+1.
    h0 = ((uint32_t)(int)floorf(sx) & (TABLE_SZ - 1)) << 2;
    h1 = ((uint32_t)(int)ceilf(sx)  & (TABLE_SZ - 1)) << 2;
    h2 = ((2654435761u * (uint32_t)(int)floorf(sy)) & (TABLE_SZ - 1)) << 2;
    h3 = ((2654435761u * (uint32_t)(int)ceilf(sy))  & (TABLE_SZ - 1)) << 2;
    h4 = ((805459861u  * (uint32_t)(int)floorf(sz)) & (TABLE_SZ - 1)) << 2;
    h5 = ((805459861u  * (uint32_t)(int)ceilf(sz))  & (TABLE_SZ - 1)) << 2;
}

__global__ __launch_bounds__(BLOCK, 4)   // VGPR cap 128; LDS allows 2 blocks/CU
void hashenc_fused(const float* __restrict__ x,
                   const __half2* __restrict__ wst,
                   float* __restrict__ out, int B)
{
    const float RES[NUM_LEVELS] = {
        16.f, 22.f, 30.f, 42.f, 58.f, 80.f, 110.f, 152.f,
        210.f, 290.f, 400.f, 553.f, 763.f, 1053.f, 1453.f, 2005.f
    };
    __shared__ __half2 tab[TABLE_SZ];            // 64 KiB, reused per level

    const int tid  = threadIdx.x;
    const int wave = tid >> 6;
    const int lane = tid & 63;
    const int b    = blockIdx.x * BLOCK + tid;
    const bool valid = (b < B);

    float px = 0.f, py = 0.f, pz = 0.f;
    if (valid) {
        px = x[3 * b + 0];
        py = x[3 * b + 1];
        pz = x[3 * b + 2];
    }

    // trilinear weights from UNSCALED position — computed ONCE per point
    float wx = px - floorf(px);
    float wy = py - floorf(py);
    float wz = pz - floorf(pz);
    float ox = 1.f - wx, oy = 1.f - wy, oz = 1.f - wz;
    float cw0 = ox * oy * oz, cw1 = wx * oy * oz;
    float cw2 = wx * wy * oz, cw3 = ox * wy * oz;
    float cw4 = ox * oy * wz, cw5 = wx * oy * wz;
    float cw6 = wx * wy * wz, cw7 = ox * wy * wz;

    float acc[2 * NUM_LEVELS];

    uint32_t h0, h1, h2, h3, h4, h5;
    make_hash(px, py, pz, RES[0], h0, h1, h2, h3, h4, h5);

    const char* tb  = (const char*)tab;
    char*       tbw = (char*)tab;
    const int   sbase = wave * 8192;             // each wave stages 8 KB

    #pragma unroll
    for (int l = 0; l < NUM_LEVELS; ++l) {
        __syncthreads();                         // prev-level gathers complete
        // ---- stage level l's 64 KiB f16 table ----
        const char* g = (const char*)(wst + (size_t)l * TABLE_SZ);
        #pragma unroll
        for (int p = 0; p < 8; ++p) {
#if __has_builtin(__builtin_amdgcn_global_load_lds)
            // per-lane global addr; wave-uniform LDS base (+ lane*16 in HW)
            __builtin_amdgcn_global_load_lds(
                (const __attribute__((address_space(1))) void*)
                    (g + sbase + p * 1024 + lane * 16),
                (__attribute__((address_space(3))) void*)(tbw + sbase + p * 1024),
                16, 0, 0);
#else
            *(float4*)(tbw + sbase + p * 1024 + lane * 16) =
                *(const float4*)(g + sbase + p * 1024 + lane * 16);
#endif
        }
        // ---- fill the staging shadow: next level's hash (x-only dependent) ----
        uint32_t n0 = 0, n1 = 0, n2 = 0, n3 = 0, n4 = 0, n5 = 0;
        if (l + 1 < NUM_LEVELS)
            make_hash(px, py, pz, RES[l + 1], n0, n1, n2, n3, n4, n5);
        __syncthreads();                         // staging visible (vmcnt drain)

        // ---- 8 LDS gathers + trilinear FMA ----
        uint32_t c0 = h0 ^ h2, c1 = h1 ^ h2, c2 = h1 ^ h3, c3 = h0 ^ h3;
        float2 f0 = __half22float2(*(const __half2*)(tb + (c0 ^ h4)));
        float2 f1 = __half22float2(*(const __half2*)(tb + (c1 ^ h4)));
        float2 f2 = __half22float2(*(const __half2*)(tb + (c2 ^ h4)));
        float2 f3 = __half22float2(*(const __half2*)(tb + (c3 ^ h4)));
        float2 f4 = __half22float2(*(const __half2*)(tb + (c0 ^ h5)));
        float2 f5 = __half22float2(*(const __half2*)(tb + (c1 ^ h5)));
        float2 f6 = __half22float2(*(const __half2*)(tb + (c2 ^ h5)));
        float2 f7 = __half22float2(*(const __half2*)(tb + (c3 ^ h5)));

        acc[2 * l] = f0.x * cw0 + f1.x * cw1 + f2.x * cw2 + f3.x * cw3
                   + f4.x * cw4 + f5.x * cw5 + f6.x * cw6 + f7.x * cw7;
        acc[2 * l + 1] = f0.y * cw0 + f1.y * cw1 + f2.y * cw2 + f3.y * cw3
                       + f4.y * cw4 + f5.y * cw5 + f6.y * cw6 + f7.y * cw7;

        if (l + 1 < NUM_LEVELS) {
            h0 = n0; h1 = n1; h2 = n2; h3 = n3; h4 = n4; h5 = n5;
        }
    }

    if (valid) {
        // 128 B contiguous per point (consecutive lanes -> consecutive lines;
        // L2/L3 merge to full lines — WRITE_SIZE ideal, verified R1/R2)
        float4* o = (float4*)(out + (size_t)b * (2 * NUM_LEVELS));
        #pragma unroll
        for (int i = 0; i < 8; ++i)
            o[i] = make_float4(acc[4 * i + 0], acc[4 * i + 1],
                               acc[4 * i + 2], acc[4 * i + 3]);
    }
}

extern "C" void kernel_launch(void* const* d_in, const int* in_sizes, int n_in,
                              void* d_out, int out_size, void* d_ws, size_t ws_size,
                              hipStream_t stream) {
    const float* x      = (const float*)d_in[0];
    const float* tables = (const float*)d_in[1];
    float* out          = (float*)d_out;
    int B = in_sizes[0] / 3;                         // 262144

    __half2* wst = (__half2*)d_ws;                   // needs 1 MB (ws is 256 MB)
    int entries = in_sizes[1] / 2;                   // 16*16384
    prep_kernel<<<entries / 256, 256, 0, stream>>>(tables, wst);

    int grid = (B + BLOCK - 1) / BLOCK;              // 512
    hashenc_fused<<<grid, BLOCK, 0, stream>>>(x, wst, out, B);
}

// Round 7
// 92.396 us; speedup vs baseline: 1.1813x; 1.1813x over previous
//
#include <hip/hip_runtime.h>
#include <hip/hip_fp16.h>
#include <stdint.h>

// MultiResolutionHashEncoding, R7: level-split two-pass (R5 shape) + TA-pipe
// diet. Closing-the-budget model (fits R1-R6): TA/L1 processes ~1 line/cyc;
// AoS x-loads cost 18 TA-cyc/wave-iter (3 loads x 6 lines) re-paid per level
// (~15 us/CU); scattered f32x2 stores cost 64 lines/wave-store (~54 us, fixed
// in R5 via ws+transpose). R7: prep kernel -> SoA x (2 lines/load) + f16
// tables; pass 1 stages 64 KiB via global_load_lds w=16, gathers from LDS,
// stores coalesced half2 to ws; pass 2 = LDS-tiled transpose (validated R5).

#define NUM_LEVELS 16
#define TABLE_SZ   16384
#define NCHUNK     32          // grid = 16 levels * 32 chunks = 512 blocks = 2/CU
#define BLOCK      512
#define TBLOCK     256

__constant__ float RESV[NUM_LEVELS] = {
    16.f, 22.f, 30.f, 42.f, 58.f, 80.f, 110.f, 152.f,
    210.f, 290.f, 400.f, 553.f, 763.f, 1053.f, 1453.f, 2005.f
};

struct PointCtx {
    uint32_t off[8];   // LDS byte offsets for 8 corners
    float    cw[8];    // trilinear corner weights
};

__device__ __forceinline__ void make_ctx(float px, float py, float pz, float r,
                                         PointCtx& c)
{
    // weights from UNSCALED position (faithful to reference)
    float wx = px - floorf(px);
    float wy = py - floorf(py);
    float wz = pz - floorf(pz);
    float ox = 1.f - wx, oy = 1.f - wy, oz = 1.f - wz;

    c.cw[0] = ox * oy * oz;
    c.cw[1] = wx * oy * oz;
    c.cw[2] = wx * wy * oz;
    c.cw[3] = ox * wy * oz;
    c.cw[4] = ox * oy * wz;
    c.cw[5] = wx * oy * wz;
    c.cw[6] = wx * wy * wz;
    c.cw[7] = ox * wy * wz;

    float sx = r * px, sy = r * py, sz = r * pz;
    // int32 wraparound hash == uint32 arithmetic; mask/shift distribute over
    // XOR -> per-component byte offsets (half2 = 4 B -> <<2). ceil, NOT lo+1.
    uint32_t mxl = ((uint32_t)(int)floorf(sx) & (TABLE_SZ - 1)) << 2;
    uint32_t mxh = ((uint32_t)(int)ceilf(sx)  & (TABLE_SZ - 1)) << 2;
    uint32_t myl = ((2654435761u * (uint32_t)(int)floorf(sy)) & (TABLE_SZ - 1)) << 2;
    uint32_t myh = ((2654435761u * (uint32_t)(int)ceilf(sy))  & (TABLE_SZ - 1)) << 2;
    uint32_t mzl = ((805459861u  * (uint32_t)(int)floorf(sz)) & (TABLE_SZ - 1)) << 2;
    uint32_t mzh = ((805459861u  * (uint32_t)(int)ceilf(sz))  & (TABLE_SZ - 1)) << 2;

    c.off[0] = mxl ^ myl ^ mzl;
    c.off[1] = mxh ^ myl ^ mzl;
    c.off[2] = mxh ^ myh ^ mzl;
    c.off[3] = mxl ^ myh ^ mzl;
    c.off[4] = mxl ^ myl ^ mzh;
    c.off[5] = mxh ^ myl ^ mzh;
    c.off[6] = mxh ^ myh ^ mzh;
    c.off[7] = mxl ^ myh ^ mzh;
}

// prep: tables f32 -> f16 half2 (1 MiB) AND x AoS -> SoA (xs/ys/zs).
__global__ __launch_bounds__(256)
void prep_kernel(const float* __restrict__ x, const float* __restrict__ tables,
                 __half2* __restrict__ tabf16,
                 float* __restrict__ xs, float* __restrict__ ys,
                 float* __restrict__ zs, int B, int entries)
{
    int e = blockIdx.x * 256 + threadIdx.x;
    if (e < entries) {
        float2 v = ((const float2*)tables)[e];
        tabf16[e] = __floats2half2_rn(v.x, v.y);
    }
    if (e < B) {
        xs[e] = x[3 * e + 0];
        ys[e] = x[3 * e + 1];
        zs[e] = x[3 * e + 2];
    }
}

// Pass 1: one level per block; f16 table staged once via global_load_lds;
// SoA x loads (2 lines/wave-load); coalesced half2 result stores.
__global__ __launch_bounds__(BLOCK, 4)
void pass1_kernel(const float* __restrict__ xs, const float* __restrict__ ys,
                  const float* __restrict__ zs,
                  const __half2* __restrict__ tabf16,
                  __half2* __restrict__ res, int B, int pts_per_block)
{
    __shared__ __half2 tab[TABLE_SZ];            // 64 KiB -> 2 blocks/CU

    const int level = blockIdx.x >> 5;           // blockIdx = level*NCHUNK + chunk
    const int chunk = blockIdx.x & (NCHUNK - 1);
    const int tid   = threadIdx.x;
    const int wave  = tid >> 6;
    const int lane  = tid & 63;

    // ---- stage: 64 KiB f16 table, global_load_lds width=16, no VALU/ds cost
    {
        const char* g = (const char*)(tabf16 + (size_t)level * TABLE_SZ);
        char* s = (char*)tab;
        const int sbase = wave * 8192;           // each of 8 waves stages 8 KiB
        #pragma unroll
        for (int p = 0; p < 8; ++p) {
#if __has_builtin(__builtin_amdgcn_global_load_lds)
            __builtin_amdgcn_global_load_lds(
                (const __attribute__((address_space(1))) void*)
                    (g + sbase + p * 1024 + lane * 16),
                (__attribute__((address_space(3))) void*)(s + sbase + p * 1024),
                16, 0, 0);
#else
            *(float4*)(s + sbase + p * 1024 + lane * 16) =
                *(const float4*)(g + sbase + p * 1024 + lane * 16);
#endif
        }
    }
    __syncthreads();

    const float r = RESV[level];
    const char* tb = (const char*)tab;
    __half2* rl = res + (size_t)level * B;

    int b = chunk * pts_per_block + tid;
    const int pair_iters = pts_per_block / (2 * BLOCK);   // 8192/1024 = 8

    for (int k = 0; k < pair_iters; ++k) {
        const int bA = b, bB = b + BLOCK;
        // SoA: 64 lanes -> 256 B contiguous = 2 lines per load (was 6 AoS)
        float pxA = xs[bA], pyA = ys[bA], pzA = zs[bA];
        float pxB = xs[bB], pyB = ys[bB], pzB = zs[bB];

        PointCtx cA, cB;
        make_ctx(pxA, pyA, pzA, r, cA);
        make_ctx(pxB, pyB, pzB, r, cB);

        // 16 ds_reads in flight before the FMA blocks
        float2 fA[8], fB[8];
        #pragma unroll
        for (int c = 0; c < 8; ++c)
            fA[c] = __half22float2(*(const __half2*)(tb + cA.off[c]));
        #pragma unroll
        for (int c = 0; c < 8; ++c)
            fB[c] = __half22float2(*(const __half2*)(tb + cB.off[c]));

        float a0 = 0.f, a1 = 0.f, b0 = 0.f, b1 = 0.f;
        #pragma unroll
        for (int c = 0; c < 8; ++c) {
            a0 += fA[c].x * cA.cw[c];
            a1 += fA[c].y * cA.cw[c];
            b0 += fB[c].x * cB.cw[c];
            b1 += fB[c].y * cB.cw[c];
        }

        // coalesced: consecutive lanes -> consecutive 4 B
        rl[bA] = __floats2half2_rn(a0, a1);
        rl[bB] = __floats2half2_rn(b0, b1);

        b += 2 * BLOCK;
    }
}

// Pass 2: res[l][b] (half2) -> out[b][2l..2l+1] (f32); fully contiguous
// float4 output runs (validated R5: absmax unchanged, WRITE_SIZE ideal).
__global__ __launch_bounds__(TBLOCK)
void transpose_kernel(const __half2* __restrict__ res,
                      float* __restrict__ out, int B)
{
    __shared__ __half2 buf[TBLOCK][NUM_LEVELS + 1];   // +1 pad: conflict-free
    const int p0 = blockIdx.x * TBLOCK;
    const int t  = threadIdx.x;

    #pragma unroll
    for (int l = 0; l < NUM_LEVELS; ++l)
        buf[t][l] = res[(size_t)l * B + p0 + t];
    __syncthreads();

    const int pl = t >> 3;   // 0..31
    const int j  = t & 7;
    float4* o = (float4*)out;
    #pragma unroll
    for (int i = 0; i < 8; ++i) {
        int p = pl + i * 32;
        float2 f0 = __half22float2(buf[p][2 * j]);
        float2 f1 = __half22float2(buf[p][2 * j + 1]);
        o[(size_t)(p0 + p) * 8 + j] = make_float4(f0.x, f0.y, f1.x, f1.y);
    }
}

// Fallback (ws too small / odd B): R3-style single pass, f32 table staged
// manually, direct scattered stores. Known-correct, slower.
__global__ __launch_bounds__(BLOCK, 4)
void fallback_kernel(const float* __restrict__ x,
                     const float* __restrict__ tables,
                     float* __restrict__ out, int B, int pts_per_block)
{
    __shared__ __half2 tab[TABLE_SZ];
    const int level = blockIdx.x >> 5;
    const int chunk = blockIdx.x & (NCHUNK - 1);
    {
        const float4* gt4 = (const float4*)(tables + (size_t)level * (TABLE_SZ * 2));
        for (int i = threadIdx.x; i < TABLE_SZ / 2; i += BLOCK) {
            float4 v = gt4[i];
            tab[2 * i]     = __floats2half2_rn(v.x, v.y);
            tab[2 * i + 1] = __floats2half2_rn(v.z, v.w);
        }
    }
    __syncthreads();
    const float r = RESV[level];
    const char* tb = (const char*)tab;
    for (int b = chunk * pts_per_block + threadIdx.x;
         b < min((chunk + 1) * pts_per_block, B); b += BLOCK) {
        PointCtx c;
        make_ctx(x[3 * b], x[3 * b + 1], x[3 * b + 2], r, c);
        float a0 = 0.f, a1 = 0.f;
        for (int i = 0; i < 8; ++i) {
            float2 f = __half22float2(*(const __half2*)(tb + c.off[i]));
            a0 += f.x * c.cw[i];
            a1 += f.y * c.cw[i];
        }
        ((float2*)out)[(size_t)b * NUM_LEVELS + level] = make_float2(a0, a1);
    }
}

extern "C" void kernel_launch(void* const* d_in, const int* in_sizes, int n_in,
                              void* d_out, int out_size, void* d_ws, size_t ws_size,
                              hipStream_t stream) {
    const float* x      = (const float*)d_in[0];
    const float* tables = (const float*)d_in[1];
    float* out          = (float*)d_out;
    int B = in_sizes[0] / 3;                          // 262144
    int entries = in_sizes[1] / 2;                    // 262144
    int pts_per_block = (B + NCHUNK - 1) / NCHUNK;    // 8192

    // ws layout: [tabf16 | xs | ys | zs | res]
    char* w = (char*)d_ws;
    size_t off_tab = 0;
    size_t off_xs  = off_tab + (size_t)entries * sizeof(__half2);
    size_t off_ys  = off_xs + (size_t)B * sizeof(float);
    size_t off_zs  = off_ys + (size_t)B * sizeof(float);
    size_t off_res = off_zs + (size_t)B * sizeof(float);
    size_t need    = off_res + (size_t)NUM_LEVELS * B * sizeof(__half2);

    dim3 grid(NUM_LEVELS * NCHUNK);
    bool shape_ok = (B % (NCHUNK * 2 * BLOCK) == 0) && (B % TBLOCK == 0);

    if (ws_size >= need && shape_ok) {
        __half2* tabf16 = (__half2*)(w + off_tab);
        float*   xs     = (float*)(w + off_xs);
        float*   ys     = (float*)(w + off_ys);
        float*   zs     = (float*)(w + off_zs);
        __half2* res    = (__half2*)(w + off_res);

        int pn = (B > entries ? B : entries);
        prep_kernel<<<(pn + 255) / 256, 256, 0, stream>>>(
            x, tables, tabf16, xs, ys, zs, B, entries);
        pass1_kernel<<<grid, BLOCK, 0, stream>>>(
            xs, ys, zs, tabf16, res, B, pts_per_block);
        transpose_kernel<<<dim3(B / TBLOCK), TBLOCK, 0, stream>>>(res, out, B);
    } else {
        fallback_kernel<<<grid, BLOCK, 0, stream>>>(x, tables, out, B, pts_per_block);
    }
}

// Round 8
// 92.318 us; speedup vs baseline: 1.1823x; 1.0008x over previous
//
#include <hip/hip_runtime.h>
#include <hip/hip_fp16.h>
#include <stdint.h>

// MultiResolutionHashEncoding, R8: occupancy max-out. Evidence R2->R7: only
// TLP moved the needle (8->16 waves/CU = +24%); ILP, store-coalescing, TA-diet
// all ~neutral; pipes idle -> stall-bound on ds_read round-trips. This round:
// BLOCK=1024 + __launch_bounds__(1024,8) -> 2 blocks/CU x 16 waves = 32
// waves/CU (HW max), VGPR budget 64 (single-point loop, no pairing, unroll 1).
// Kept (validated): prep SoA x + f16 tables, global_load_lds w=16 staging,
// coalesced half2 res stores, LDS-tiled transpose pass.

#define NUM_LEVELS 16
#define TABLE_SZ   16384
#define NCHUNK     32          // grid = 16 levels * 32 chunks = 512 blocks = 2/CU
#define BLOCK      1024
#define TBLOCK     256

__constant__ float RESV[NUM_LEVELS] = {
    16.f, 22.f, 30.f, 42.f, 58.f, 80.f, 110.f, 152.f,
    210.f, 290.f, 400.f, 553.f, 763.f, 1053.f, 1453.f, 2005.f
};

// prep: tables f32 -> f16 half2 (1 MiB) AND x AoS -> SoA (xs/ys/zs).
__global__ __launch_bounds__(256)
void prep_kernel(const float* __restrict__ x, const float* __restrict__ tables,
                 __half2* __restrict__ tabf16,
                 float* __restrict__ xs, float* __restrict__ ys,
                 float* __restrict__ zs, int B, int entries)
{
    int e = blockIdx.x * 256 + threadIdx.x;
    if (e < entries) {
        float2 v = ((const float2*)tables)[e];
        tabf16[e] = __floats2half2_rn(v.x, v.y);
    }
    if (e < B) {
        xs[e] = x[3 * e + 0];
        ys[e] = x[3 * e + 1];
        zs[e] = x[3 * e + 2];
    }
}

// Pass 1: one level per block, 1024 threads, 32 waves/CU.
__global__ __launch_bounds__(BLOCK, 8)   // 8 waves/EU -> VGPR cap 64
void pass1_kernel(const float* __restrict__ xs, const float* __restrict__ ys,
                  const float* __restrict__ zs,
                  const __half2* __restrict__ tabf16,
                  __half2* __restrict__ res, int B, int pts_per_block)
{
    __shared__ __half2 tab[TABLE_SZ];            // 64 KiB -> 2 blocks/CU

    const int level = blockIdx.x >> 5;           // blockIdx = level*NCHUNK + chunk
    const int chunk = blockIdx.x & (NCHUNK - 1);
    const int tid   = threadIdx.x;
    const int wave  = tid >> 6;                  // 0..15
    const int lane  = tid & 63;

    // ---- stage 64 KiB f16 table via global_load_lds w=16 (each wave 4 KiB)
    {
        const char* g = (const char*)(tabf16 + (size_t)level * TABLE_SZ);
        char* s = (char*)tab;
        const int sbase = wave * 4096;
        #pragma unroll
        for (int p = 0; p < 4; ++p) {
#if __has_builtin(__builtin_amdgcn_global_load_lds)
            __builtin_amdgcn_global_load_lds(
                (const __attribute__((address_space(1))) void*)
                    (g + sbase + p * 1024 + lane * 16),
                (__attribute__((address_space(3))) void*)(s + sbase + p * 1024),
                16, 0, 0);
#else
            *(float4*)(s + sbase + p * 1024 + lane * 16) =
                *(const float4*)(g + sbase + p * 1024 + lane * 16);
#endif
        }
    }
    __syncthreads();

    const float r = RESV[level];
    const char* tb = (const char*)tab;
    __half2* rl = res + (size_t)level * B;

    int b = chunk * pts_per_block + tid;
    const int iters = pts_per_block / BLOCK;     // 8192/1024 = 8

    #pragma unroll 1                             // keep VGPR <= 64: no unroll
    for (int k = 0; k < iters; ++k) {
        // SoA: 64 lanes -> 256 B contiguous = 2 lines per load
        float px = xs[b], py = ys[b], pz = zs[b];

        // trilinear weights from UNSCALED position (faithful to reference)
        float wx = px - floorf(px);
        float wy = py - floorf(py);
        float wz = pz - floorf(pz);
        float ox = 1.f - wx, oy = 1.f - wy, oz = 1.f - wz;

        float sx = r * px, sy = r * py, sz = r * pz;
        // int32 wraparound hash == uint32; mask/shift distribute over XOR ->
        // pre-shifted byte offsets (half2 = 4 B -> <<2). ceil, NOT lo+1.
        uint32_t h0 = ((uint32_t)(int)floorf(sx) & (TABLE_SZ - 1)) << 2;
        uint32_t h1 = ((uint32_t)(int)ceilf(sx)  & (TABLE_SZ - 1)) << 2;
        uint32_t h2 = ((2654435761u * (uint32_t)(int)floorf(sy)) & (TABLE_SZ - 1)) << 2;
        uint32_t h3 = ((2654435761u * (uint32_t)(int)ceilf(sy))  & (TABLE_SZ - 1)) << 2;
        uint32_t h4 = ((805459861u  * (uint32_t)(int)floorf(sz)) & (TABLE_SZ - 1)) << 2;
        uint32_t h5 = ((805459861u  * (uint32_t)(int)ceilf(sz))  & (TABLE_SZ - 1)) << 2;

        uint32_t c0 = h0 ^ h2, c1 = h1 ^ h2, c2 = h1 ^ h3, c3 = h0 ^ h3;

        // 8 ds_read_b32 issued back-to-back (compiler emits fine lgkmcnt)
        __half2 g0 = *(const __half2*)(tb + (c0 ^ h4));
        __half2 g1 = *(const __half2*)(tb + (c1 ^ h4));
        __half2 g2 = *(const __half2*)(tb + (c2 ^ h4));
        __half2 g3 = *(const __half2*)(tb + (c3 ^ h4));
        __half2 g4 = *(const __half2*)(tb + (c0 ^ h5));
        __half2 g5 = *(const __half2*)(tb + (c1 ^ h5));
        __half2 g6 = *(const __half2*)(tb + (c2 ^ h5));
        __half2 g7 = *(const __half2*)(tb + (c3 ^ h5));

        float a0, a1;
        {
            float2 f;
            f = __half22float2(g0); float w = ox * oy * oz; a0  = f.x * w; a1  = f.y * w;
            f = __half22float2(g1);       w = wx * oy * oz; a0 += f.x * w; a1 += f.y * w;
            f = __half22float2(g2);       w = wx * wy * oz; a0 += f.x * w; a1 += f.y * w;
            f = __half22float2(g3);       w = ox * wy * oz; a0 += f.x * w; a1 += f.y * w;
            f = __half22float2(g4);       w = ox * oy * wz; a0 += f.x * w; a1 += f.y * w;
            f = __half22float2(g5);       w = wx * oy * wz; a0 += f.x * w; a1 += f.y * w;
            f = __half22float2(g6);       w = wx * wy * wz; a0 += f.x * w; a1 += f.y * w;
            f = __half22float2(g7);       w = ox * wy * wz; a0 += f.x * w; a1 += f.y * w;
        }

        // coalesced: consecutive lanes -> consecutive 4 B
        rl[b] = __floats2half2_rn(a0, a1);
        b += BLOCK;
    }
}

// Pass 2: res[l][b] (half2) -> out[b][2l..2l+1] (f32); fully contiguous
// float4 output runs (validated R5/R7: absmax unchanged, WRITE_SIZE ideal).
__global__ __launch_bounds__(TBLOCK)
void transpose_kernel(const __half2* __restrict__ res,
                      float* __restrict__ out, int B)
{
    __shared__ __half2 buf[TBLOCK][NUM_LEVELS + 1];   // +1 pad: conflict-free
    const int p0 = blockIdx.x * TBLOCK;
    const int t  = threadIdx.x;

    #pragma unroll
    for (int l = 0; l < NUM_LEVELS; ++l)
        buf[t][l] = res[(size_t)l * B + p0 + t];
    __syncthreads();

    const int pl = t >> 3;   // 0..31
    const int j  = t & 7;
    float4* o = (float4*)out;
    #pragma unroll
    for (int i = 0; i < 8; ++i) {
        int p = pl + i * 32;
        float2 f0 = __half22float2(buf[p][2 * j]);
        float2 f1 = __half22float2(buf[p][2 * j + 1]);
        o[(size_t)(p0 + p) * 8 + j] = make_float4(f0.x, f0.y, f1.x, f1.y);
    }
}

// Fallback (ws too small / odd B): single pass, direct scattered stores.
__global__ __launch_bounds__(512, 4)
void fallback_kernel(const float* __restrict__ x,
                     const float* __restrict__ tables,
                     float* __restrict__ out, int B, int pts_per_block)
{
    __shared__ __half2 tab[TABLE_SZ];
    const int level = blockIdx.x >> 5;
    const int chunk = blockIdx.x & (NCHUNK - 1);
    {
        const float4* gt4 = (const float4*)(tables + (size_t)level * (TABLE_SZ * 2));
        for (int i = threadIdx.x; i < TABLE_SZ / 2; i += 512) {
            float4 v = gt4[i];
            tab[2 * i]     = __floats2half2_rn(v.x, v.y);
            tab[2 * i + 1] = __floats2half2_rn(v.z, v.w);
        }
    }
    __syncthreads();
    const float r = RESV[level];
    const char* tb = (const char*)tab;
    int lim = min((chunk + 1) * pts_per_block, B);
    for (int b = chunk * pts_per_block + threadIdx.x; b < lim; b += 512) {
        float px = x[3 * b], py = x[3 * b + 1], pz = x[3 * b + 2];
        float wx = px - floorf(px), wy = py - floorf(py), wz = pz - floorf(pz);
        float ox = 1.f - wx, oy = 1.f - wy, oz = 1.f - wz;
        float sx = r * px, sy = r * py, sz = r * pz;
        uint32_t h0 = ((uint32_t)(int)floorf(sx) & (TABLE_SZ - 1)) << 2;
        uint32_t h1 = ((uint32_t)(int)ceilf(sx)  & (TABLE_SZ - 1)) << 2;
        uint32_t h2 = ((2654435761u * (uint32_t)(int)floorf(sy)) & (TABLE_SZ - 1)) << 2;
        uint32_t h3 = ((2654435761u * (uint32_t)(int)ceilf(sy))  & (TABLE_SZ - 1)) << 2;
        uint32_t h4 = ((805459861u  * (uint32_t)(int)floorf(sz)) & (TABLE_SZ - 1)) << 2;
        uint32_t h5 = ((805459861u  * (uint32_t)(int)ceilf(sz))  & (TABLE_SZ - 1)) << 2;
        uint32_t c0 = h0 ^ h2, c1 = h1 ^ h2, c2 = h1 ^ h3, c3 = h0 ^ h3;
        float a0 = 0.f, a1 = 0.f;
        float cw[8] = { ox*oy*oz, wx*oy*oz, wx*wy*oz, ox*wy*oz,
                        ox*oy*wz, wx*oy*wz, wx*wy*wz, ox*wy*wz };
        uint32_t off[8] = { c0^h4, c1^h4, c2^h4, c3^h4, c0^h5, c1^h5, c2^h5, c3^h5 };
        for (int i = 0; i < 8; ++i) {
            float2 f = __half22float2(*(const __half2*)(tb + off[i]));
            a0 += f.x * cw[i];
            a1 += f.y * cw[i];
        }
        ((float2*)out)[(size_t)b * NUM_LEVELS + level] = make_float2(a0, a1);
    }
}

extern "C" void kernel_launch(void* const* d_in, const int* in_sizes, int n_in,
                              void* d_out, int out_size, void* d_ws, size_t ws_size,
                              hipStream_t stream) {
    const float* x      = (const float*)d_in[0];
    const float* tables = (const float*)d_in[1];
    float* out          = (float*)d_out;
    int B = in_sizes[0] / 3;                          // 262144
    int entries = in_sizes[1] / 2;                    // 262144
    int pts_per_block = (B + NCHUNK - 1) / NCHUNK;    // 8192

    // ws layout: [tabf16 | xs | ys | zs | res]
    char* w = (char*)d_ws;
    size_t off_tab = 0;
    size_t off_xs  = off_tab + (size_t)entries * sizeof(__half2);
    size_t off_ys  = off_xs + (size_t)B * sizeof(float);
    size_t off_zs  = off_ys + (size_t)B * sizeof(float);
    size_t off_res = off_zs + (size_t)B * sizeof(float);
    size_t need    = off_res + (size_t)NUM_LEVELS * B * sizeof(__half2);

    dim3 grid(NUM_LEVELS * NCHUNK);
    bool shape_ok = (B % (NCHUNK * BLOCK) == 0) && (B % TBLOCK == 0);

    if (ws_size >= need && shape_ok) {
        __half2* tabf16 = (__half2*)(w + off_tab);
        float*   xs     = (float*)(w + off_xs);
        float*   ys     = (float*)(w + off_ys);
        float*   zs     = (float*)(w + off_zs);
        __half2* res    = (__half2*)(w + off_res);

        int pn = (B > entries ? B : entries);
        prep_kernel<<<(pn + 255) / 256, 256, 0, stream>>>(
            x, tables, tabf16, xs, ys, zs, B, entries);
        pass1_kernel<<<grid, BLOCK, 0, stream>>>(
            xs, ys, zs, tabf16, res, B, pts_per_block);
        transpose_kernel<<<dim3(B / TBLOCK), TBLOCK, 0, stream>>>(res, out, B);
    } else {
        fallback_kernel<<<grid, 512, 0, stream>>>(x, tables, out, B, pts_per_block);
    }
}